// Round 5
// baseline (2621.882 us; speedup 1.0000x reference)
//
#include <hip/hip_runtime.h>

#define SEQ  4096
#define HID  128
#define BT   4            // real batch columns per block (replicated into 16 MFMA cols)
#define NBLK (256 / BT)   // 64 blocks

typedef _Float16 half8 __attribute__((ext_vector_type(8)));
typedef _Float16 half4 __attribute__((ext_vector_type(4)));
typedef float    f32x4 __attribute__((ext_vector_type(4)));

#define L2E  1.44269504088896340736f   // log2(e)
#define L2E2 2.88539008177792681472f   // 2*log2(e)

__device__ __forceinline__ float exp2_(float x) { return __builtin_amdgcn_exp2f(x); }
__device__ __forceinline__ float rcp_(float x)  { return __builtin_amdgcn_rcpf(x); }
// inputs pre-scaled by log2e: sigmoid(x) = 1/(1+2^-x')
__device__ __forceinline__ float sigm2(float xp) { return rcp_(1.f + exp2_(-xp)); }
// input pre-scaled by 2*log2e: tanh(x) = 1 - 2/(1+2^x')
__device__ __forceinline__ float tanh2(float xp) { return 1.f - 2.f * rcp_(1.f + exp2_(xp)); }

// One block = 4 batch elements, 8 waves. Wave w owns gate M-tiles {w,w+8,w+16,w+24}
// (all four gates for hidden rows [16w,16w+16)). B operand replicated over the 4
// column groups (col = n&3): each lane computes its own column's rows, epilogue is
// lane-local. Input projection enters as the MFMA C-operand, built on the VALU.
__global__ __launch_bounds__(512, 2)
void lstm_mfma(const float* __restrict__ inputs,   // (B,S,3)
               const float* __restrict__ hx0,      // (B,128)
               const float* __restrict__ cx0,      // (B,128)
               const float* __restrict__ W_inp,    // (64,3)
               const float* __restrict__ b_inp,    // (64)
               const float* __restrict__ W_ih,     // (512,64)
               const float* __restrict__ b_ih,     // (512)
               const float* __restrict__ W_hh,     // (512,128)
               const float* __restrict__ b_hh,     // (512)
               const float* __restrict__ W_out,    // (40,128)
               const float* __restrict__ b_out,    // (40)
               float*       __restrict__ out)      // (B,40)
{
    // h state, double-buffered, transposed: element (kt,q,c,i) = h[k=kt*32+q*8+i][col c]
    __shared__ _Float16 xvT[2][4][4][4][8];   // 2 KB
    // input ring: slot s&15 holds {u0,u1,u2,1} per col (filled 8 steps ahead)
    __shared__ _Float16 uring[16][4][4];      // 512 B
    __shared__ float    hxf[BT][HID + 4];     // final fp32 hx for out-projection

    const int tid  = threadIdx.x;
    const int w    = tid >> 6;        // wave 0..7
    const int lane = tid & 63;
    const int q    = lane >> 4;       // 0..3
    const int n    = lane & 15;
    const int bbase = blockIdx.x * BT;

    const int hi   = (n >> 3) & 1;
    const int b2   = (n >> 2) & 1;
    const int col  = n & 3;                   // this lane's batch column
    const int hrow = w * 16 + q * 4 + hi * 2 + b2;  // this lane's hidden row (bijective)

    // ---- A fragments in registers, pre-scaled by log2e (2*log2e for g gate) ----
    // Element i of lane-group q at K-tile kt holds Whh_scaled[m][kt*32 + q*8 + i];
    // B uses the identical slot->k convention, so any HW k-permutation cancels.
    half8 A[4][4];
    #pragma unroll
    for (int t = 0; t < 4; ++t) {
        const float scl = (t == 2) ? L2E2 : L2E;
        const int m = t * 128 + w * 16 + n;          // gate row for A fragments
        const float* whr = W_hh + m * HID;
        #pragma unroll
        for (int kt = 0; kt < 4; ++kt) {
            half8 a;
            #pragma unroll
            for (int i = 0; i < 8; ++i) a[i] = (_Float16)(whr[kt * 32 + q * 8 + i] * scl);
            A[t][kt] = a;
        }
    }

    // ---- weff for the C-operand init: rows 4q..4q+3 of each gate tile ----------
    // wf[t][r] = {wx,wy,wz,beff} (scaled) for gate row m2 = t*128 + w*16 + 4q + r
    float4 wf[4][4];
    #pragma unroll
    for (int t = 0; t < 4; ++t) {
        const float scl = (t == 2) ? L2E2 : L2E;
        #pragma unroll
        for (int r = 0; r < 4; ++r) {
            const int m2 = t * 128 + w * 16 + q * 4 + r;
            const float* wir = W_ih + m2 * 64;
            float wx = 0.f, wy = 0.f, wz = 0.f, bb = 0.f;
            for (int hh = 0; hh < 64; ++hh) {
                float wv = wir[hh];
                wx += wv * W_inp[hh * 3 + 0];
                wy += wv * W_inp[hh * 3 + 1];
                wz += wv * W_inp[hh * 3 + 2];
                bb += wv * b_inp[hh];
            }
            bb += b_ih[m2] + b_hh[m2];
            wf[t][r] = make_float4(wx * scl, wy * scl, wz * scl, bb * scl);
        }
    }

    // ---- Loader lane mapping (wave 1): 96 floats = 8 steps x 4 cols x 3 --------
    const int  F0 = lane, F1 = lane + 64;
    const int  col0 = F0 / 24, rem0 = F0 % 24, slot0 = rem0 / 3, wi0 = rem0 % 3;
    const bool f1v = (F1 < 96);
    const int  col1 = f1v ? F1 / 24 : 0, rem1 = f1v ? F1 % 24 : 0;
    const int  slot1 = rem1 / 3, wi1 = rem1 % 3;
    const float* up0 = inputs + (size_t)(bbase + col0) * (SEQ * 3) + wi0;
    const float* up1 = inputs + (size_t)(bbase + col1) * (SEQ * 3) + wi1;

    // ---- Init LDS --------------------------------------------------------------
    for (int i = tid; i < 2 * 4 * 4 * 4 * 8; i += 512) ((_Float16*)xvT)[i] = (_Float16)0.f;
    if (tid < 64) uring[tid >> 2][tid & 3][3] = (_Float16)1.f;
    __syncthreads();
    for (int idx = tid; idx < BT * HID; idx += 512) {
        int c = idx >> 7, h = idx & 127;
        xvT[0][h >> 5][(h >> 3) & 3][c][h & 7] = (_Float16)hx0[(bbase + c) * HID + h];
    }
    if (w == 1) {   // ring slots 0..7 = steps 0..7
        uring[slot0][col0][wi0] = (_Float16)up0[slot0 * 3];
        if (f1v) uring[slot1][col1][wi1] = (_Float16)up1[slot1 * 3];
    }
    float creg = cx0[(bbase + col) * HID + hrow];
    __syncthreads();

    const int kw = hrow >> 5, qw = (hrow >> 3) & 3, iw = hrow & 7;
    float pend0 = 0.f, pend1 = 0.f, hl = 0.f;

    // ---- Recurrent loop: 1 barrier per step ------------------------------------
    for (int s = 0; s < SEQ; ++s) {
        _Float16 (*br)[4][4][8] = xvT[s & 1];
        _Float16 (*bw)[4][4][8] = xvT[(s + 1) & 1];

        // deep input prefetch: issue at s%8==0 (8 steps ahead), LDS-write at s%8==4
        if (w == 1) {
            if ((s & 7) == 0) {
                int st0 = s + 8 + slot0; st0 = st0 > SEQ - 1 ? SEQ - 1 : st0;
                pend0 = up0[st0 * 3];
                if (f1v) { int st1 = s + 8 + slot1; st1 = st1 > SEQ - 1 ? SEQ - 1 : st1;
                           pend1 = up1[st1 * 3]; }
            } else if ((s & 7) == 4) {
                uring[(s + 4 + slot0) & 15][col0][wi0] = (_Float16)pend0;
                if (f1v) uring[(s + 4 + slot1) & 15][col1][wi1] = (_Float16)pend1;
            }
        }

        // u first (b64 broadcast read), then C-operand init on the VALU while
        // the B-fragment ds_reads are in flight.
        half4 u4 = *reinterpret_cast<const half4*>(&uring[s & 15][col][0]);

        half8 B[4];
        #pragma unroll
        for (int kt = 0; kt < 4; ++kt)
            B[kt] = *reinterpret_cast<const half8*>(&br[kt][q][col][0]);

        const float u0 = (float)u4[0], u1 = (float)u4[1], u2 = (float)u4[2];
        f32x4 acc[4];
        #pragma unroll
        for (int t = 0; t < 4; ++t) {
            #pragma unroll
            for (int r = 0; r < 4; ++r) {
                const float4 wfv = wf[t][r];
                acc[t][r] = fmaf(wfv.x, u0, fmaf(wfv.y, u1, fmaf(wfv.z, u2, wfv.w)));
            }
        }

        // gates = Whh_scaled @ h  on top of the input-proj init
        #pragma unroll
        for (int t = 0; t < 4; ++t) {
            #pragma unroll
            for (int kt = 0; kt < 4; ++kt)
                acc[t] = __builtin_amdgcn_mfma_f32_16x16x32_f16(A[t][kt], B[kt], acc[t], 0, 0, 0);
        }

        // lane-local row select (row r = 2*hi + b2), pure cndmask
        float g4[4];
        #pragma unroll
        for (int t = 0; t < 4; ++t) {
            float ra = b2 ? acc[t][1] : acc[t][0];
            float rb = b2 ? acc[t][3] : acc[t][2];
            g4[t] = hi ? rb : ra;
        }

        // one LSTM update per lane (fp32 state); all exp are exp2, no pre-muls
        float iv = sigm2(g4[0]), fv = sigm2(g4[1]);
        float gv = tanh2(g4[2]), ov = sigm2(g4[3]);
        creg = fv * creg + iv * gv;
        float h = ov * (1.f - 2.f * rcp_(1.f + exp2_(creg * L2E2)));
        hl = h;

        bw[kw][qw][col][iw] = (_Float16)h;   // 512 lanes cover all 128 rows x 4 cols
        __syncthreads();
    }

    // ---- Out projection: out[b] = W_out @ hx_last + b_out ----------------------
    hxf[col][hrow] = hl;
    __syncthreads();
    if (tid < BT * 40) {
        int bl = tid / 40, o = tid % 40;
        const float* wr = W_out + o * HID;
        float a = b_out[o];
        #pragma unroll 8
        for (int k = 0; k < HID; ++k) a += wr[k] * hxf[bl][k];
        out[(bbase + bl) * 40 + o] = a;
    }
}

extern "C" void kernel_launch(void* const* d_in, const int* in_sizes, int n_in,
                              void* d_out, int out_size, void* d_ws, size_t ws_size,
                              hipStream_t stream) {
    const float* inputs = (const float*)d_in[0];
    const float* hx0    = (const float*)d_in[1];
    const float* cx0    = (const float*)d_in[2];
    const float* W_inp  = (const float*)d_in[3];
    const float* b_inp  = (const float*)d_in[4];
    const float* W_ih   = (const float*)d_in[5];
    const float* b_ih   = (const float*)d_in[6];
    const float* W_hh   = (const float*)d_in[7];
    const float* b_hh   = (const float*)d_in[8];
    const float* W_out  = (const float*)d_in[9];
    const float* b_out  = (const float*)d_in[10];
    float* out = (float*)d_out;

    lstm_mfma<<<NBLK, 512, 0, stream>>>(inputs, hx0, cx0, W_inp, b_inp, W_ih, b_ih,
                                        W_hh, b_hh, W_out, b_out, out);
}